// Round 9
// baseline (75.729 us; speedup 1.0000x reference)
//
#include <hip/hip_runtime.h>

// LowRankSig_HigherOrder: B=32, T=2048, F=64 (time + 63), K=10 tensors, U=64 units.
// Round 9 = round 8 (MFMA bf16 2-term split einsum, affine-scan maps) with the
// three latency-bound fixes:
//  1. k-phase split (nt {0,1,2} / {3,4,5} / {6,7,8,9}): peak acc 160->64 AGPR,
//     and the per-ks B-frag working set (24-32 KB) now fits L1 across the ks
//     loop -> kwb pulled once/WG from L2 (was ~4x thrash = ~1.3 GB aggregate).
//  2. in-register run composition via __shfl_xor(.,32) + sequential in-lane
//     compose -> the 69632 B LDS map buffer is gone. LDS = 32768 B
//     (bf16 hi/lo 16 KB + raw fp32 tile 16.6 KB; 8.7 KB maps overlay raw).
//     4 WG/CU instead of 2.
//  3. coalesced staging: the 65x63 X tile is one contiguous span -> coalesced
//     scalar loads into LDS raw, then a diff+bf16-split pass (row-0 dup makes
//     the t=0 diff zero automatically). Barriers 6 -> 3.
// C/D layout (HW-verified m74/m101): col=lane&31, row=(reg&3)+8*(reg>>2)+4*hi8.
// Maps/compose family validated rounds 1-8; combine kernel unchanged.

#define TT 2048
#define NFX 63
#define KT 10
#define NU 64
#define NQ 17
#define NCC 32       // 64-row chunks per batch (ws map layout)

#define MAPS_BYTES (32u * NCC * NQ * NU * 4u)          // 4,456,448 B
#define KWB_ELEMS  (640u * 64u)                        // per plane

typedef __attribute__((ext_vector_type(16))) float f32x16v;
typedef __attribute__((ext_vector_type(8)))  short bf16x8v;

enum {Qo=0, Qa1, Qa3, QaA, Qa6, QaP, QaQ, Qd1, Qd3, QdA, Qd6, QdP, QdQ,
      QtA3, QtP6, QtQP, QtQ6};

__device__ __forceinline__ unsigned short bf16_rne(float x) {
  unsigned int u = __float_as_uint(x);
  unsigned int r = (u + 0x7FFFu + ((u >> 16) & 1u)) >> 16;
  return (unsigned short)r;
}
__device__ __forceinline__ float bf16f(unsigned short h) {
  return __uint_as_float(((unsigned int)h) << 16);
}

// compose earlier map q1 with later map q2 -> r (family closed; r2/r7-validated)
__device__ __forceinline__ void compose_maps(const float* q1, const float* q2,
                                             float* r)
{
  r[Qo]  = q1[Qo] + q2[Qo]
         + q2[Qa1]*q1[Qd1] + q2[Qa3]*q1[Qd3] + q2[QaA]*q1[QdA]
         + q2[Qa6]*q1[Qd6] + q2[QaP]*q1[QdP] + q2[QaQ]*q1[QdQ];
  r[Qa1] = q1[Qa1] + q2[Qa1];
  r[Qa3] = q1[Qa3] + q2[Qa3] + q1[QtA3]*q2[QaA];
  r[QaA] = q1[QaA] + q2[QaA];
  r[Qa6] = q1[Qa6] + q2[Qa6] + q1[QtP6]*q2[QaP] + q1[QtQ6]*q2[QaQ];
  r[QaP] = q1[QaP] + q2[QaP] + q1[QtQP]*q2[QaQ];
  r[QaQ] = q1[QaQ] + q2[QaQ];
  r[Qd1] = q1[Qd1] + q2[Qd1];
  r[Qd3] = q1[Qd3] + q2[Qd3];
  r[QdA] = q1[QdA] + q2[QdA] + q2[QtA3]*q1[Qd3];
  r[Qd6] = q1[Qd6] + q2[Qd6];
  r[QdP] = q1[QdP] + q2[QdP] + q2[QtP6]*q1[Qd6];
  r[QdQ] = q1[QdQ] + q2[QdQ] + q2[QtQP]*q1[QdP] + q2[QtQ6]*q1[Qd6];
  r[QtA3] = q1[QtA3] + q2[QtA3];
  r[QtP6] = q1[QtP6] + q2[QtP6];
  r[QtQP] = q1[QtQP] + q2[QtQP];
  r[QtQ6] = q1[QtQ6] + q2[QtQ6] + q2[QtQP]*q1[QtP6];
}

// ---- prep: split Kw into bf16 hi/lo planes, layout [n = k*64+u][f] ----
__global__ __launch_bounds__(256)
void lrsig_prep_kernel(const float* __restrict__ Kw,
                       unsigned short* __restrict__ kwb)
{
  int e = blockIdx.x * 256 + threadIdx.x;    // 0..40959
  int n = e >> 6, f = e & 63;
  int k = n >> 6, u = n & 63;
  float x = Kw[(f * KT + k) * NU + u];
  unsigned short hi = bf16_rne(x);
  unsigned short lo = bf16_rne(x - bf16f(hi));
  kwb[(size_t)n * 64 + f] = hi;
  kwb[KWB_ELEMS + (size_t)n * 64 + f] = lo;
}

// one k-phase: acc[t] = dXa_rows x Kw[:, (KBASE+t)*64 + colbase], K=64
template<int KBASE, int NNT>
__device__ __forceinline__ void mfma_phase(const char* smem,
    const unsigned short* __restrict__ kwb, int row, int colbase, int hi8,
    f32x16v (&acc)[NNT])
{
#pragma unroll
  for (int t = 0; t < NNT; ++t)
#pragma unroll
    for (int i = 0; i < 16; ++i) acc[t][i] = 0.f;
#pragma unroll
  for (int ks = 0; ks < 4; ++ks) {
    const int f0 = ks * 16 + hi8 * 8;
    const int abyte = row * 128 + ((2 * f0) ^ ((row & 7) << 4));
    bf16x8v ah = *(const bf16x8v*)(smem + abyte);
    bf16x8v al = *(const bf16x8v*)(smem + 8192 + abyte);
#pragma unroll
    for (int t = 0; t < NNT; ++t) {
      const int n = (KBASE + t) * 64 + colbase;
      const unsigned short* bp = kwb + (size_t)n * 64 + f0;
      bf16x8v bh = *(const bf16x8v*)(bp);
      bf16x8v bl = *(const bf16x8v*)(bp + KWB_ELEMS);
      acc[t] = __builtin_amdgcn_mfma_f32_32x32x16_bf16(ah, bh, acc[t], 0, 0, 0);
      acc[t] = __builtin_amdgcn_mfma_f32_32x32x16_bf16(al, bh, acc[t], 0, 0, 0);
      acc[t] = __builtin_amdgcn_mfma_f32_32x32x16_bf16(ah, bl, acc[t], 0, 0, 0);
    }
  }
}

__global__ __launch_bounds__(256)
void lrsig_chunk_kernel(const float* __restrict__ X,
                        const unsigned short* __restrict__ kwb,
                        float* __restrict__ wmaps)
{
  // 32768 B total:
  //   bytes [0,8192)      : dXa bf16 hi plane, swizzled [64 rows][128 B]
  //   bytes [8192,16384)  : lo plane
  //   floats [4096,8191]  : raw fp32 X tile (4095 used) during staging;
  //                         after MFMA reused as map slots [2 rt][NQ][NU]
  __shared__ __align__(16) float smemf[8192];
  char* smem = (char*)smemf;
  float* rawf = smemf + 4096;

  const int b   = blockIdx.y;
  const int c   = blockIdx.x;        // 0..31, 64 rows per WG
  const int tid = threadIdx.x;
  const int l   = tid & 63;
  const int w   = tid >> 6;          // wave 0..3
  const int rt  = w >> 1;            // row-tile (rows rt*32 .. +31)
  const int ub  = w & 1;             // u-block  (u = ub*32 + col)
  const int col = l & 31;
  const int hi8 = l >> 5;
  const int t0  = c * 64;

  // ---- 1. coalesced load of the raw tile: rows t0-1 .. t0+63 (65 x 63) ----
  {
    const float* Xb = X + (size_t)b * TT * NFX;
    const size_t srcbase = (c == 0) ? 0 : ((size_t)(t0 - 1) * NFX);
    for (int i = tid; i < 65 * NFX; i += 256) {
      size_t off = (c == 0) ? (size_t)((i < NFX) ? i : i - NFX) : (srcbase + i);
      rawf[i] = Xb[off];
    }
  }
  __syncthreads();

  // ---- 2. diff + bf16 hi/lo split into swizzled planes ----
  for (int e = tid; e < 64 * NFX; e += 256) {
    int r2 = e / NFX;
    int c2 = e - r2 * NFX;             // feature-1 (features 1..63)
    float d = rawf[e + NFX] - rawf[e]; // row-0 dup makes t=0 diff zero
    unsigned short h  = bf16_rne(d);
    unsigned short lo = bf16_rne(d - bf16f(h));
    int byte = r2 * 128 + ((2 * (c2 + 1)) ^ ((r2 & 7) << 4));
    *(unsigned short*)(smem + byte)        = h;
    *(unsigned short*)(smem + 8192 + byte) = lo;
  }
  if (tid < 64) {                      // time feature f=0
    int r2 = tid;
    float d = (t0 + r2 == 0) ? 0.f : (2.0f / 2047.0f);
    unsigned short h  = bf16_rne(d);
    unsigned short lo = bf16_rne(d - bf16f(h));
    int byte = r2 * 128 + ((0) ^ ((r2 & 7) << 4));
    *(unsigned short*)(smem + byte)        = h;
    *(unsigned short*)(smem + 8192 + byte) = lo;
  }
  __syncthreads();

  const int row = rt * 32 + col;
  const int colbase = ub * 32 + col;

  // ---- phase A: k 0..2, scan chain A per 4-row run ----
  float Ao[4], Aa1[4], Ad1[4];
  {
    f32x16v acc[3];
    mfma_phase<0, 3>(smem, kwb, row, colbase, hi8, acc);
#pragma unroll
    for (int j = 0; j < 4; ++j) {
      float o = 0.f, a1 = 0.f, lc1 = 0.f;
#pragma unroll
      for (int i = 0; i < 4; ++i) {
        const int r = 4 * j + i;
        float m0 = acc[0][r], m1 = acc[1][r], m2 = acc[2][r];
        o   += m0 + m2 * (lc1 + 0.5f * m1);
        a1  += m2;
        lc1 += m1;
      }
      Ao[j] = o; Aa1[j] = a1; Ad1[j] = lc1;
    }
  }

  // ---- phase B: k 3..5, scan chain B per run ----
  float Ba3[4], BaA[4], Bd3[4], BdA[4], BtA3[4];
  {
    f32x16v acc[3];
    mfma_phase<3, 3>(smem, kwb, row, colbase, hi8, acc);
#pragma unroll
    for (int j = 0; j < 4; ++j) {
      float o = 0.f, a3 = 0.f, aA = 0.f, lc3 = 0.f, lcA = 0.f, g4 = 0.f;
#pragma unroll
      for (int i = 0; i < 4; ++i) {
        const int r = 4 * j + i;
        float m3 = acc[0][r], m4 = acc[1][r], m5 = acc[2][r];
        float s0 = m4 * lc3;
        float s1 = 0.5f * m4 * m3;
        o   += m5 * (lcA + 0.5f * s0 + (1.f/3.f) * s1);
        a3  += m5 * (g4 + 0.5f * m4);
        aA  += m5;
        lcA += s0 + s1;
        g4  += m4;
        lc3 += m3;
      }
      Ao[j] += o;
      Ba3[j] = a3; BaA[j] = aA; Bd3[j] = lc3; BdA[j] = lcA; BtA3[j] = g4;
    }
  }

  // ---- phase C: k 6..9, scan chain C, assemble run maps, compose in-reg ----
  float tot[NQ];
  {
    f32x16v acc[4];
    mfma_phase<6, 4>(smem, kwb, row, colbase, hi8, acc);
#pragma unroll
    for (int j = 0; j < 4; ++j) {
      float o = 0.f, a6 = 0.f, aP = 0.f, aQ = 0.f;
      float lc6 = 0.f, lcP = 0.f, lcQ = 0.f, g7 = 0.f, g8 = 0.f, hh = 0.f;
#pragma unroll
      for (int i = 0; i < 4; ++i) {
        const int r = 4 * j + i;
        float m6 = acc[0][r], m7 = acc[1][r], m8 = acc[2][r], m9 = acc[3][r];
        float p0 = m7 * lc6;
        float p1 = 0.5f * m7 * m6;
        float q0 = m8 * lcP;
        float q1 = 0.5f * m8 * p0;
        float q2 = (1.f/3.f) * m8 * p1;
        o   += m9 * (lcQ + 0.5f * q0 + (1.f/3.f) * q1 + 0.25f * q2);
        a6  += m9 * (hh + m8 * (0.5f * g7 + (1.f/6.f) * m7));
        aP  += m9 * (g8 + 0.5f * m8);
        aQ  += m9;
        hh  += m8 * (g7 + 0.5f * m7);   // exclusive g7, before update
        lcP += p0 + p1;
        lcQ += q0 + q1 + q2;
        g7 += m7; g8 += m8; lc6 += m6;
      }
      // full 17-param map for this 4-row run (rows 4g..4g+3, g = 2j+hi8)
      float mj[NQ];
      mj[Qo] = Ao[j] + o;
      mj[Qa1] = Aa1[j]; mj[Qa3] = Ba3[j]; mj[QaA] = BaA[j];
      mj[Qa6] = a6;     mj[QaP] = aP;     mj[QaQ] = aQ;
      mj[Qd1] = Ad1[j]; mj[Qd3] = Bd3[j]; mj[QdA] = BdA[j];
      mj[Qd6] = lc6;    mj[QdP] = lcP;    mj[QdQ] = lcQ;
      mj[QtA3] = BtA3[j]; mj[QtP6] = g7;  mj[QtQP] = g8; mj[QtQ6] = hh;

      // exchange with partner lane (g even <-> g odd) and compose 8-row map
      float q1v[NQ], q2v[NQ], m8r[NQ];
#pragma unroll
      for (int q = 0; q < NQ; ++q) {
        float oth = __shfl_xor(mj[q], 32);
        q1v[q] = hi8 ? oth : mj[q];       // even g = earlier rows
        q2v[q] = hi8 ? mj[q] : oth;
      }
      compose_maps(q1v, q2v, m8r);

      if (j == 0) {
#pragma unroll
        for (int q = 0; q < NQ; ++q) tot[q] = m8r[q];
      } else {
        float nt_[NQ];
        compose_maps(tot, m8r, nt_);
#pragma unroll
        for (int q = 0; q < NQ; ++q) tot[q] = nt_[q];
      }
    }
  }

  // ---- write the two 32-row maps (one per rt) into LDS (raw area is dead) --
  if (hi8 == 0) {
    float* p = &rawf[(rt * NQ) * NU + colbase];
#pragma unroll
    for (int q = 0; q < NQ; ++q) p[q * NU] = tot[q];
  }
  __syncthreads();

  // ---- final compose rt0 o rt1 -> 64-row WG map -> ws ----
  if (tid < NU) {
    const int uu = tid;
    float q1v[NQ], q2v[NQ], rv[NQ];
#pragma unroll
    for (int q = 0; q < NQ; ++q) {
      q1v[q] = rawf[(0 * NQ + q) * NU + uu];
      q2v[q] = rawf[(1 * NQ + q) * NU + uu];
    }
    compose_maps(q1v, q2v, rv);
    float* p = &wmaps[(((size_t)b * NCC + c) * NQ) * NU + uu];
#pragma unroll
    for (int q = 0; q < NQ; ++q) p[q * NU] = rv[q];
  }
}

__global__ __launch_bounds__(256)
void lrsig_combine_kernel(const float* __restrict__ ws, float* __restrict__ out)
{
  const int gid = blockIdx.x * blockDim.x + threadIdx.x;   // 0..2047
  const int u = gid & 63;
  const int b = gid >> 6;
  float c1 = 0.f, c3 = 0.f, cA = 0.f, c6 = 0.f, cP = 0.f, cQ = 0.f, o = 0.f;
  for (int cc = 0; cc < NCC; ++cc) {
    const float* p = &ws[(((size_t)b * NCC + cc) * NQ) * NU + u];
    float q[NQ];
#pragma unroll
    for (int i = 0; i < NQ; ++i) q[i] = p[i * NU];
    o  += q[0] + q[1]*c1 + q[2]*c3 + q[3]*cA + q[4]*c6 + q[5]*cP + q[6]*cQ;
    cA += q[13]*c3 + q[9];             // uses c3_in
    cQ += q[15]*cP + q[16]*c6 + q[12]; // uses cP_in, c6_in
    cP += q[14]*c6 + q[11];            // uses c6_in
    c1 += q[7]; c3 += q[8]; c6 += q[10];
  }
  out[gid] = o;
}

extern "C" void kernel_launch(void* const* d_in, const int* in_sizes, int n_in,
                              void* d_out, int out_size, void* d_ws, size_t ws_size,
                              hipStream_t stream) {
  const float* X  = (const float*)d_in[0];   // (32, 2048, 63) fp32
  const float* Kw = (const float*)d_in[1];   // (64, 10, 64)   fp32
  float* out = (float*)d_out;                // (32, 64)       fp32
  float* wmaps = (float*)d_ws;               // maps: 4.45 MB
  unsigned short* kwb = (unsigned short*)((char*)d_ws + MAPS_BYTES); // 160 KB

  hipLaunchKernelGGL(lrsig_prep_kernel, dim3(160), dim3(256), 0, stream,
                     Kw, kwb);
  hipLaunchKernelGGL(lrsig_chunk_kernel, dim3(NCC, 32), dim3(256), 0, stream,
                     X, kwb, wmaps);
  hipLaunchKernelGGL(lrsig_combine_kernel, dim3(8), dim3(256), 0, stream,
                     wmaps, out);
}

// Round 10
// 60.100 us; speedup vs baseline: 1.2600x; 1.2600x over previous
//
#include <hip/hip_runtime.h>

// LowRankSig_HigherOrder: B=32, T=2048, F=64 (time + 63), K=10 tensors, U=64 units.
// Round 10 = round 9 (MFMA bf16 2-term split einsum, k-phase split, in-register
// run composition) with the B-fragment load pattern fixed:
//   r9's kwb layout [n][f] made lane l load 16 B at stride 128 B across lanes
//   -> every global_load_dwordx4 touched 32 cache lines (~2560 line
//   transactions per wave, unhideable at 2 waves/SIMD). That was the 65 us.
//   kwb is now FRAG-MAJOR: [plane][nt][ub][ks][lane][8 bf16], so each (nt,ks)
//   B-load is 64 lanes x contiguous 16 B = one coalesced 1 KB wave-load.
//   Pure permutation -- same (n,f) per lane, validated math untouched.
// C/D layout (HW-verified m74/m101): col=lane&31, row=(reg&3)+8*(reg>>2)+4*hi8.

#define TT 2048
#define NFX 63
#define KT 10
#define NU 64
#define NQ 17
#define NCC 32       // 64-row chunks per batch (ws map layout)

#define MAPS_BYTES (32u * NCC * NQ * NU * 4u)          // 4,456,448 B
#define PLANE      40960u                              // elems per bf16 plane

typedef __attribute__((ext_vector_type(16))) float f32x16v;
typedef __attribute__((ext_vector_type(8)))  short bf16x8v;

enum {Qo=0, Qa1, Qa3, QaA, Qa6, QaP, QaQ, Qd1, Qd3, QdA, Qd6, QdP, QdQ,
      QtA3, QtP6, QtQP, QtQ6};

__device__ __forceinline__ unsigned short bf16_rne(float x) {
  unsigned int u = __float_as_uint(x);
  unsigned int r = (u + 0x7FFFu + ((u >> 16) & 1u)) >> 16;
  return (unsigned short)r;
}
__device__ __forceinline__ float bf16f(unsigned short h) {
  return __uint_as_float(((unsigned int)h) << 16);
}

// compose earlier map q1 with later map q2 -> r (family closed; r2/r7-validated)
__device__ __forceinline__ void compose_maps(const float* q1, const float* q2,
                                             float* r)
{
  r[Qo]  = q1[Qo] + q2[Qo]
         + q2[Qa1]*q1[Qd1] + q2[Qa3]*q1[Qd3] + q2[QaA]*q1[QdA]
         + q2[Qa6]*q1[Qd6] + q2[QaP]*q1[QdP] + q2[QaQ]*q1[QdQ];
  r[Qa1] = q1[Qa1] + q2[Qa1];
  r[Qa3] = q1[Qa3] + q2[Qa3] + q1[QtA3]*q2[QaA];
  r[QaA] = q1[QaA] + q2[QaA];
  r[Qa6] = q1[Qa6] + q2[Qa6] + q1[QtP6]*q2[QaP] + q1[QtQ6]*q2[QaQ];
  r[QaP] = q1[QaP] + q2[QaP] + q1[QtQP]*q2[QaQ];
  r[QaQ] = q1[QaQ] + q2[QaQ];
  r[Qd1] = q1[Qd1] + q2[Qd1];
  r[Qd3] = q1[Qd3] + q2[Qd3];
  r[QdA] = q1[QdA] + q2[QdA] + q2[QtA3]*q1[Qd3];
  r[Qd6] = q1[Qd6] + q2[Qd6];
  r[QdP] = q1[QdP] + q2[QdP] + q2[QtP6]*q1[Qd6];
  r[QdQ] = q1[QdQ] + q2[QdQ] + q2[QtQP]*q1[QdP] + q2[QtQ6]*q1[Qd6];
  r[QtA3] = q1[QtA3] + q2[QtA3];
  r[QtP6] = q1[QtP6] + q2[QtP6];
  r[QtQP] = q1[QtQP] + q2[QtQP];
  r[QtQ6] = q1[QtQ6] + q2[QtQ6] + q2[QtQP]*q1[QtP6];
}

// ---- prep: split Kw into bf16 hi/lo planes, FRAG-MAJOR layout:
//      idx = (((nt*2 + ub)*4 + ks)*64 + lane)*8 + j
//      where lane=(hi8*32+col): f = ks*16 + hi8*8 + j, u = ub*32 + col, k = nt.
__global__ __launch_bounds__(256)
void lrsig_prep_kernel(const float* __restrict__ Kw,
                       unsigned short* __restrict__ kwb)
{
  int e = blockIdx.x * 256 + threadIdx.x;    // 0..40959 (destination index)
  int j  = e & 7;
  int l  = (e >> 3) & 63;
  int ks = (e >> 9) & 3;
  int ub = (e >> 11) & 1;
  int nt = e >> 12;
  int f = ks * 16 + (l >> 5) * 8 + j;
  int u = ub * 32 + (l & 31);
  float x = Kw[(f * KT + nt) * NU + u];
  unsigned short hi = bf16_rne(x);
  unsigned short lo = bf16_rne(x - bf16f(hi));
  kwb[e] = hi;
  kwb[PLANE + e] = lo;
}

// one k-phase: acc[t] = dXa_rows x Kw[:, k-tiles KBASE..], K=64, coalesced B
template<int KBASE, int NNT>
__device__ __forceinline__ void mfma_phase(const char* smem,
    const unsigned short* __restrict__ kwb, int row, int l, int ub, int hi8,
    f32x16v (&acc)[NNT])
{
#pragma unroll
  for (int t = 0; t < NNT; ++t)
#pragma unroll
    for (int i = 0; i < 16; ++i) acc[t][i] = 0.f;
#pragma unroll
  for (int ks = 0; ks < 4; ++ks) {
    const int f0 = ks * 16 + hi8 * 8;
    const int abyte = row * 128 + ((2 * f0) ^ ((row & 7) << 4));
    bf16x8v ah = *(const bf16x8v*)(smem + abyte);
    bf16x8v al = *(const bf16x8v*)(smem + 8192 + abyte);
#pragma unroll
    for (int t = 0; t < NNT; ++t) {
      const unsigned short* bp =
          kwb + ((((KBASE + t) * 2 + ub) * 4 + ks) * 512) + l * 8;
      bf16x8v bh = *(const bf16x8v*)(bp);
      bf16x8v bl = *(const bf16x8v*)(bp + PLANE);
      acc[t] = __builtin_amdgcn_mfma_f32_32x32x16_bf16(ah, bh, acc[t], 0, 0, 0);
      acc[t] = __builtin_amdgcn_mfma_f32_32x32x16_bf16(al, bh, acc[t], 0, 0, 0);
      acc[t] = __builtin_amdgcn_mfma_f32_32x32x16_bf16(ah, bl, acc[t], 0, 0, 0);
    }
  }
}

__global__ __launch_bounds__(256)
void lrsig_chunk_kernel(const float* __restrict__ X,
                        const unsigned short* __restrict__ kwb,
                        float* __restrict__ wmaps)
{
  // 32768 B total:
  //   bytes [0,8192)      : dXa bf16 hi plane, swizzled [64 rows][128 B]
  //   bytes [8192,16384)  : lo plane
  //   floats [4096,8191]  : raw fp32 X tile during staging; after MFMA reused
  //                         as map slots [2 rt][NQ][NU]
  __shared__ __align__(16) float smemf[8192];
  char* smem = (char*)smemf;
  float* rawf = smemf + 4096;

  const int b   = blockIdx.y;
  const int c   = blockIdx.x;        // 0..31, 64 rows per WG
  const int tid = threadIdx.x;
  const int l   = tid & 63;
  const int w   = tid >> 6;          // wave 0..3
  const int rt  = w >> 1;            // row-tile (rows rt*32 .. +31)
  const int ub  = w & 1;             // u-block  (u = ub*32 + col)
  const int col = l & 31;
  const int hi8 = l >> 5;
  const int t0  = c * 64;

  // ---- 1. coalesced load of the raw tile: rows t0-1 .. t0+63 (65 x 63) ----
  {
    const float* Xb = X + (size_t)b * TT * NFX;
    const size_t srcbase = (c == 0) ? 0 : ((size_t)(t0 - 1) * NFX);
    for (int i = tid; i < 65 * NFX; i += 256) {
      size_t off = (c == 0) ? (size_t)((i < NFX) ? i : i - NFX) : (srcbase + i);
      rawf[i] = Xb[off];
    }
  }
  __syncthreads();

  // ---- 2. diff + bf16 hi/lo split into swizzled planes ----
  for (int e = tid; e < 64 * NFX; e += 256) {
    int r2 = e / NFX;
    int c2 = e - r2 * NFX;             // feature-1 (features 1..63)
    float d = rawf[e + NFX] - rawf[e]; // row-0 dup makes t=0 diff zero
    unsigned short h  = bf16_rne(d);
    unsigned short lo = bf16_rne(d - bf16f(h));
    int byte = r2 * 128 + ((2 * (c2 + 1)) ^ ((r2 & 7) << 4));
    *(unsigned short*)(smem + byte)        = h;
    *(unsigned short*)(smem + 8192 + byte) = lo;
  }
  if (tid < 64) {                      // time feature f=0
    int r2 = tid;
    float d = (t0 + r2 == 0) ? 0.f : (2.0f / 2047.0f);
    unsigned short h  = bf16_rne(d);
    unsigned short lo = bf16_rne(d - bf16f(h));
    int byte = r2 * 128 + ((0) ^ ((r2 & 7) << 4));
    *(unsigned short*)(smem + byte)        = h;
    *(unsigned short*)(smem + 8192 + byte) = lo;
  }
  __syncthreads();

  const int row = rt * 32 + col;
  const int colbase = ub * 32 + col;

  // ---- phase A: k 0..2, scan chain A per 4-row run ----
  float Ao[4], Aa1[4], Ad1[4];
  {
    f32x16v acc[3];
    mfma_phase<0, 3>(smem, kwb, row, l, ub, hi8, acc);
#pragma unroll
    for (int j = 0; j < 4; ++j) {
      float o = 0.f, a1 = 0.f, lc1 = 0.f;
#pragma unroll
      for (int i = 0; i < 4; ++i) {
        const int r = 4 * j + i;
        float m0 = acc[0][r], m1 = acc[1][r], m2 = acc[2][r];
        o   += m0 + m2 * (lc1 + 0.5f * m1);
        a1  += m2;
        lc1 += m1;
      }
      Ao[j] = o; Aa1[j] = a1; Ad1[j] = lc1;
    }
  }

  // ---- phase B: k 3..5, scan chain B per run ----
  float Ba3[4], BaA[4], Bd3[4], BdA[4], BtA3[4];
  {
    f32x16v acc[3];
    mfma_phase<3, 3>(smem, kwb, row, l, ub, hi8, acc);
#pragma unroll
    for (int j = 0; j < 4; ++j) {
      float o = 0.f, a3 = 0.f, aA = 0.f, lc3 = 0.f, lcA = 0.f, g4 = 0.f;
#pragma unroll
      for (int i = 0; i < 4; ++i) {
        const int r = 4 * j + i;
        float m3 = acc[0][r], m4 = acc[1][r], m5 = acc[2][r];
        float s0 = m4 * lc3;
        float s1 = 0.5f * m4 * m3;
        o   += m5 * (lcA + 0.5f * s0 + (1.f/3.f) * s1);
        a3  += m5 * (g4 + 0.5f * m4);
        aA  += m5;
        lcA += s0 + s1;
        g4  += m4;
        lc3 += m3;
      }
      Ao[j] += o;
      Ba3[j] = a3; BaA[j] = aA; Bd3[j] = lc3; BdA[j] = lcA; BtA3[j] = g4;
    }
  }

  // ---- phase C: k 6..9, scan chain C, assemble run maps, compose in-reg ----
  float tot[NQ];
  {
    f32x16v acc[4];
    mfma_phase<6, 4>(smem, kwb, row, l, ub, hi8, acc);
#pragma unroll
    for (int j = 0; j < 4; ++j) {
      float o = 0.f, a6 = 0.f, aP = 0.f, aQ = 0.f;
      float lc6 = 0.f, lcP = 0.f, lcQ = 0.f, g7 = 0.f, g8 = 0.f, hh = 0.f;
#pragma unroll
      for (int i = 0; i < 4; ++i) {
        const int r = 4 * j + i;
        float m6 = acc[0][r], m7 = acc[1][r], m8 = acc[2][r], m9 = acc[3][r];
        float p0 = m7 * lc6;
        float p1 = 0.5f * m7 * m6;
        float q0 = m8 * lcP;
        float q1 = 0.5f * m8 * p0;
        float q2 = (1.f/3.f) * m8 * p1;
        o   += m9 * (lcQ + 0.5f * q0 + (1.f/3.f) * q1 + 0.25f * q2);
        a6  += m9 * (hh + m8 * (0.5f * g7 + (1.f/6.f) * m7));
        aP  += m9 * (g8 + 0.5f * m8);
        aQ  += m9;
        hh  += m8 * (g7 + 0.5f * m7);   // exclusive g7, before update
        lcP += p0 + p1;
        lcQ += q0 + q1 + q2;
        g7 += m7; g8 += m8; lc6 += m6;
      }
      // full 17-param map for this 4-row run (rows 4g..4g+3, g = 2j+hi8)
      float mj[NQ];
      mj[Qo] = Ao[j] + o;
      mj[Qa1] = Aa1[j]; mj[Qa3] = Ba3[j]; mj[QaA] = BaA[j];
      mj[Qa6] = a6;     mj[QaP] = aP;     mj[QaQ] = aQ;
      mj[Qd1] = Ad1[j]; mj[Qd3] = Bd3[j]; mj[QdA] = BdA[j];
      mj[Qd6] = lc6;    mj[QdP] = lcP;    mj[QdQ] = lcQ;
      mj[QtA3] = BtA3[j]; mj[QtP6] = g7;  mj[QtQP] = g8; mj[QtQ6] = hh;

      // exchange with partner lane (g even <-> g odd) and compose 8-row map
      float q1v[NQ], q2v[NQ], m8r[NQ];
#pragma unroll
      for (int q = 0; q < NQ; ++q) {
        float oth = __shfl_xor(mj[q], 32);
        q1v[q] = hi8 ? oth : mj[q];       // even g = earlier rows
        q2v[q] = hi8 ? mj[q] : oth;
      }
      compose_maps(q1v, q2v, m8r);

      if (j == 0) {
#pragma unroll
        for (int q = 0; q < NQ; ++q) tot[q] = m8r[q];
      } else {
        float nt_[NQ];
        compose_maps(tot, m8r, nt_);
#pragma unroll
        for (int q = 0; q < NQ; ++q) tot[q] = nt_[q];
      }
    }
  }

  // ---- write the two 32-row maps (one per rt) into LDS (raw area is dead) --
  if (hi8 == 0) {
    float* p = &rawf[(rt * NQ) * NU + colbase];
#pragma unroll
    for (int q = 0; q < NQ; ++q) p[q * NU] = tot[q];
  }
  __syncthreads();

  // ---- final compose rt0 o rt1 -> 64-row WG map -> ws ----
  if (tid < NU) {
    const int uu = tid;
    float q1v[NQ], q2v[NQ], rv[NQ];
#pragma unroll
    for (int q = 0; q < NQ; ++q) {
      q1v[q] = rawf[(0 * NQ + q) * NU + uu];
      q2v[q] = rawf[(1 * NQ + q) * NU + uu];
    }
    compose_maps(q1v, q2v, rv);
    float* p = &wmaps[(((size_t)b * NCC + c) * NQ) * NU + uu];
#pragma unroll
    for (int q = 0; q < NQ; ++q) p[q * NU] = rv[q];
  }
}

__global__ __launch_bounds__(256)
void lrsig_combine_kernel(const float* __restrict__ ws, float* __restrict__ out)
{
  const int gid = blockIdx.x * blockDim.x + threadIdx.x;   // 0..2047
  const int u = gid & 63;
  const int b = gid >> 6;
  float c1 = 0.f, c3 = 0.f, cA = 0.f, c6 = 0.f, cP = 0.f, cQ = 0.f, o = 0.f;
#pragma unroll 4
  for (int cc = 0; cc < NCC; ++cc) {
    const float* p = &ws[(((size_t)b * NCC + cc) * NQ) * NU + u];
    float q[NQ];
#pragma unroll
    for (int i = 0; i < NQ; ++i) q[i] = p[i * NU];
    o  += q[0] + q[1]*c1 + q[2]*c3 + q[3]*cA + q[4]*c6 + q[5]*cP + q[6]*cQ;
    cA += q[13]*c3 + q[9];             // uses c3_in
    cQ += q[15]*cP + q[16]*c6 + q[12]; // uses cP_in, c6_in
    cP += q[14]*c6 + q[11];            // uses c6_in
    c1 += q[7]; c3 += q[8]; c6 += q[10];
  }
  out[gid] = o;
}

extern "C" void kernel_launch(void* const* d_in, const int* in_sizes, int n_in,
                              void* d_out, int out_size, void* d_ws, size_t ws_size,
                              hipStream_t stream) {
  const float* X  = (const float*)d_in[0];   // (32, 2048, 63) fp32
  const float* Kw = (const float*)d_in[1];   // (64, 10, 64)   fp32
  float* out = (float*)d_out;                // (32, 64)       fp32
  float* wmaps = (float*)d_ws;               // maps: 4.45 MB
  unsigned short* kwb = (unsigned short*)((char*)d_ws + MAPS_BYTES); // 160 KB

  hipLaunchKernelGGL(lrsig_prep_kernel, dim3(160), dim3(256), 0, stream,
                     Kw, kwb);
  hipLaunchKernelGGL(lrsig_chunk_kernel, dim3(NCC, 32), dim3(256), 0, stream,
                     X, kwb, wmaps);
  hipLaunchKernelGGL(lrsig_combine_kernel, dim3(8), dim3(256), 0, stream,
                     wmaps, out);
}

// Round 11
// 48.349 us; speedup vs baseline: 1.5663x; 1.2430x over previous
//
#include <hip/hip_runtime.h>

// LowRankSig_HigherOrder: B=32, T=2048, F=64 (time + 63), K=10 tensors, U=64 units.
// Round 11 = round 10 (MFMA bf16 2-term split, frag-major coalesced B, k-phase
// split, in-register run composition) + latency hiding:
//  - phase-A B-frags (24 x 16 B) issued BEFORE the staging barrier: their
//    latency lands under the X-tile staging (barrier drains vmcnt anyway).
//  - A-frags (8 x ds_read_b128) loaded ONCE for all 3 phases (same row).
//  - phases B/C: double-buffered nt-prefetch (next nt's 8 B-frags load while
//    current nt's 12 MFMAs run) -> ~1 un-hidden latency per phase, not per nt.
//  - staging + diff/split loops batch-issue loads into regs, then store
//    (16 serialized load->store rounds -> 1 round).
//  - combine split into partial (8-map folds, 8192 lanes) + final (4-fold),
//    replacing the 32-deep serial per-thread chain.
// C/D layout (HW-verified m74/m101): col=lane&31, row=(reg&3)+8*(reg>>2)+4*hi8.
// Maps/compose family validated rounds 1-10.

#define TT 2048
#define NFX 63
#define KT 10
#define NU 64
#define NQ 17
#define NCC 32       // 64-row chunks per batch (ws map layout)
#define NSEG 4       // partial-fold segments (8 maps each)

#define MAPS_BYTES (32u * NCC * NQ * NU * 4u)          // 4,456,448 B
#define KWB_BYTES  (2u * 40960u * 2u)                  // 163,840 B
#define PLANE      40960u                              // elems per bf16 plane

typedef __attribute__((ext_vector_type(16))) float f32x16v;
typedef __attribute__((ext_vector_type(8)))  short bf16x8v;

enum {Qo=0, Qa1, Qa3, QaA, Qa6, QaP, QaQ, Qd1, Qd3, QdA, Qd6, QdP, QdQ,
      QtA3, QtP6, QtQP, QtQ6};

__device__ __forceinline__ unsigned short bf16_rne(float x) {
  unsigned int u = __float_as_uint(x);
  unsigned int r = (u + 0x7FFFu + ((u >> 16) & 1u)) >> 16;
  return (unsigned short)r;
}
__device__ __forceinline__ float bf16f(unsigned short h) {
  return __uint_as_float(((unsigned int)h) << 16);
}

// compose earlier map q1 with later map q2 -> r (family closed; r2/r7-validated)
__device__ __forceinline__ void compose_maps(const float* q1, const float* q2,
                                             float* r)
{
  r[Qo]  = q1[Qo] + q2[Qo]
         + q2[Qa1]*q1[Qd1] + q2[Qa3]*q1[Qd3] + q2[QaA]*q1[QdA]
         + q2[Qa6]*q1[Qd6] + q2[QaP]*q1[QdP] + q2[QaQ]*q1[QdQ];
  r[Qa1] = q1[Qa1] + q2[Qa1];
  r[Qa3] = q1[Qa3] + q2[Qa3] + q1[QtA3]*q2[QaA];
  r[QaA] = q1[QaA] + q2[QaA];
  r[Qa6] = q1[Qa6] + q2[Qa6] + q1[QtP6]*q2[QaP] + q1[QtQ6]*q2[QaQ];
  r[QaP] = q1[QaP] + q2[QaP] + q1[QtQP]*q2[QaQ];
  r[QaQ] = q1[QaQ] + q2[QaQ];
  r[Qd1] = q1[Qd1] + q2[Qd1];
  r[Qd3] = q1[Qd3] + q2[Qd3];
  r[QdA] = q1[QdA] + q2[QdA] + q2[QtA3]*q1[Qd3];
  r[Qd6] = q1[Qd6] + q2[Qd6];
  r[QdP] = q1[QdP] + q2[QdP] + q2[QtP6]*q1[Qd6];
  r[QdQ] = q1[QdQ] + q2[QdQ] + q2[QtQP]*q1[QdP] + q2[QtQ6]*q1[Qd6];
  r[QtA3] = q1[QtA3] + q2[QtA3];
  r[QtP6] = q1[QtP6] + q2[QtP6];
  r[QtQP] = q1[QtQP] + q2[QtQP];
  r[QtQ6] = q1[QtQ6] + q2[QtQ6] + q2[QtQP]*q1[QtP6];
}

// ---- prep: split Kw into bf16 hi/lo planes, FRAG-MAJOR layout:
//      idx = (((nt*2 + ub)*4 + ks)*64 + lane)*8 + j
//      lane=(hi8*32+col): f = ks*16 + hi8*8 + j, u = ub*32 + col, k = nt.
__global__ __launch_bounds__(256)
void lrsig_prep_kernel(const float* __restrict__ Kw,
                       unsigned short* __restrict__ kwb)
{
  int e = blockIdx.x * 256 + threadIdx.x;    // 0..40959 (destination index)
  int j  = e & 7;
  int l  = (e >> 3) & 63;
  int ks = (e >> 9) & 3;
  int ub = (e >> 11) & 1;
  int nt = e >> 12;
  int f = ks * 16 + (l >> 5) * 8 + j;
  int u = ub * 32 + (l & 31);
  float x = Kw[(f * KT + nt) * NU + u];
  unsigned short hi = bf16_rne(x);
  unsigned short lo = bf16_rne(x - bf16f(hi));
  kwb[e] = hi;
  kwb[PLANE + e] = lo;
}

// phases B/C: double-buffered nt-prefetch, A-frags preloaded
template<int KBASE, int NNT>
__device__ __forceinline__ void mfma_phase_pf(
    const unsigned short* __restrict__ kwb,
    const bf16x8v (&ah)[4], const bf16x8v (&al)[4],
    int l, int ub, f32x16v (&acc)[NNT])
{
#pragma unroll
  for (int t = 0; t < NNT; ++t)
#pragma unroll
    for (int i = 0; i < 16; ++i) acc[t][i] = 0.f;

  bf16x8v bh[2][4], bl[2][4];
#pragma unroll
  for (int ks = 0; ks < 4; ++ks) {
    const unsigned short* bp =
        kwb + (((KBASE * 2 + ub) * 4 + ks) * 512) + l * 8;
    bh[0][ks] = *(const bf16x8v*)(bp);
    bl[0][ks] = *(const bf16x8v*)(bp + PLANE);
  }
#pragma unroll
  for (int t = 0; t < NNT; ++t) {
    if (t + 1 < NNT) {
#pragma unroll
      for (int ks = 0; ks < 4; ++ks) {
        const unsigned short* bp =
            kwb + ((((KBASE + t + 1) * 2 + ub) * 4 + ks) * 512) + l * 8;
        bh[(t + 1) & 1][ks] = *(const bf16x8v*)(bp);
        bl[(t + 1) & 1][ks] = *(const bf16x8v*)(bp + PLANE);
      }
    }
#pragma unroll
    for (int ks = 0; ks < 4; ++ks) {
      acc[t] = __builtin_amdgcn_mfma_f32_32x32x16_bf16(ah[ks], bh[t & 1][ks], acc[t], 0, 0, 0);
      acc[t] = __builtin_amdgcn_mfma_f32_32x32x16_bf16(al[ks], bh[t & 1][ks], acc[t], 0, 0, 0);
      acc[t] = __builtin_amdgcn_mfma_f32_32x32x16_bf16(ah[ks], bl[t & 1][ks], acc[t], 0, 0, 0);
    }
  }
}

__global__ __launch_bounds__(256)
void lrsig_chunk_kernel(const float* __restrict__ X,
                        const unsigned short* __restrict__ kwb,
                        float* __restrict__ wmaps)
{
  // 32768 B total:
  //   bytes [0,8192)      : dXa bf16 hi plane, swizzled [64 rows][128 B]
  //   bytes [8192,16384)  : lo plane
  //   floats [4096,8191]  : raw fp32 X tile during staging; after MFMA reused
  //                         as map slots [2 rt][NQ][NU]
  __shared__ __align__(16) float smemf[8192];
  char* smem = (char*)smemf;
  float* rawf = smemf + 4096;

  const int b   = blockIdx.y;
  const int c   = blockIdx.x;        // 0..31, 64 rows per WG
  const int tid = threadIdx.x;
  const int l   = tid & 63;
  const int w   = tid >> 6;          // wave 0..3
  const int rt  = w >> 1;            // row-tile (rows rt*32 .. +31)
  const int ub  = w & 1;             // u-block  (u = ub*32 + col)
  const int col = l & 31;
  const int hi8 = l >> 5;
  const int t0  = c * 64;

  // ---- 1. batch-issue the 16 staging loads (rows t0-1 .. t0+63, 65x63) ----
  float sv[16];
  {
    const float* Xb = X + (size_t)b * TT * NFX;
    const int base = (t0 - 1) * NFX;
#pragma unroll
    for (int ii = 0; ii < 16; ++ii) {
      int i = tid + ii * 256;
      int off = base + i + ((c == 0 && i < NFX) ? NFX : 0); // c==0: dup row 0
      sv[ii] = (i < 65 * NFX) ? Xb[off] : 0.f;
    }
  }

  // ---- 2. issue phase-A B-frags now; they complete under staging ----
  bf16x8v bhA[3][4], blA[3][4];
#pragma unroll
  for (int t = 0; t < 3; ++t)
#pragma unroll
    for (int ks = 0; ks < 4; ++ks) {
      const unsigned short* bp = kwb + (((t * 2 + ub) * 4 + ks) * 512) + l * 8;
      bhA[t][ks] = *(const bf16x8v*)(bp);
      blA[t][ks] = *(const bf16x8v*)(bp + PLANE);
    }

  // ---- 3. store staged tile to LDS ----
#pragma unroll
  for (int ii = 0; ii < 16; ++ii) {
    int i = tid + ii * 256;
    if (i < 65 * NFX) rawf[i] = sv[ii];
  }
  __syncthreads();

  // ---- 4. diff + bf16 hi/lo split into swizzled planes (batched reads) ----
  {
    float v0[16], v1[16];
#pragma unroll
    for (int ii = 0; ii < 16; ++ii) {
      int e = tid + ii * 256;
      if (e < 64 * NFX) { v0[ii] = rawf[e]; v1[ii] = rawf[e + NFX]; }
    }
#pragma unroll
    for (int ii = 0; ii < 16; ++ii) {
      int e = tid + ii * 256;
      if (e < 64 * NFX) {
        int r2 = e / NFX;
        int c2 = e - r2 * NFX;             // feature-1 (features 1..63)
        float d = v1[ii] - v0[ii];         // row-0 dup makes t=0 diff zero
        unsigned short h  = bf16_rne(d);
        unsigned short lo = bf16_rne(d - bf16f(h));
        int byte = r2 * 128 + ((2 * (c2 + 1)) ^ ((r2 & 7) << 4));
        *(unsigned short*)(smem + byte)        = h;
        *(unsigned short*)(smem + 8192 + byte) = lo;
      }
    }
  }
  if (tid < 64) {                      // time feature f=0
    int r2 = tid;
    float d = (t0 + r2 == 0) ? 0.f : (2.0f / 2047.0f);
    unsigned short h  = bf16_rne(d);
    unsigned short lo = bf16_rne(d - bf16f(h));
    int byte = r2 * 128 + ((0) ^ ((r2 & 7) << 4));
    *(unsigned short*)(smem + byte)        = h;
    *(unsigned short*)(smem + 8192 + byte) = lo;
  }
  __syncthreads();

  const int row = rt * 32 + col;
  const int colbase = ub * 32 + col;

  // ---- A-frags once for all phases (same row) ----
  bf16x8v ah[4], al[4];
#pragma unroll
  for (int ks = 0; ks < 4; ++ks) {
    const int f0 = ks * 16 + hi8 * 8;
    const int abyte = row * 128 + ((2 * f0) ^ ((row & 7) << 4));
    ah[ks] = *(const bf16x8v*)(smem + abyte);
    al[ks] = *(const bf16x8v*)(smem + 8192 + abyte);
  }

  // ---- phase A: k 0..2 (B preloaded), scan chain A per 4-row run ----
  float Ao[4], Aa1[4], Ad1[4];
  {
    f32x16v acc[3];
#pragma unroll
    for (int t = 0; t < 3; ++t)
#pragma unroll
      for (int i = 0; i < 16; ++i) acc[t][i] = 0.f;
#pragma unroll
    for (int ks = 0; ks < 4; ++ks)
#pragma unroll
      for (int t = 0; t < 3; ++t) {
        acc[t] = __builtin_amdgcn_mfma_f32_32x32x16_bf16(ah[ks], bhA[t][ks], acc[t], 0, 0, 0);
        acc[t] = __builtin_amdgcn_mfma_f32_32x32x16_bf16(al[ks], bhA[t][ks], acc[t], 0, 0, 0);
        acc[t] = __builtin_amdgcn_mfma_f32_32x32x16_bf16(ah[ks], blA[t][ks], acc[t], 0, 0, 0);
      }
#pragma unroll
    for (int j = 0; j < 4; ++j) {
      float o = 0.f, a1 = 0.f, lc1 = 0.f;
#pragma unroll
      for (int i = 0; i < 4; ++i) {
        const int r = 4 * j + i;
        float m0 = acc[0][r], m1 = acc[1][r], m2 = acc[2][r];
        o   += m0 + m2 * (lc1 + 0.5f * m1);
        a1  += m2;
        lc1 += m1;
      }
      Ao[j] = o; Aa1[j] = a1; Ad1[j] = lc1;
    }
  }

  // ---- phase B: k 3..5, scan chain B per run ----
  float Ba3[4], BaA[4], Bd3[4], BdA[4], BtA3[4];
  {
    f32x16v acc[3];
    mfma_phase_pf<3, 3>(kwb, ah, al, l, ub, acc);
#pragma unroll
    for (int j = 0; j < 4; ++j) {
      float o = 0.f, a3 = 0.f, aA = 0.f, lc3 = 0.f, lcA = 0.f, g4 = 0.f;
#pragma unroll
      for (int i = 0; i < 4; ++i) {
        const int r = 4 * j + i;
        float m3 = acc[0][r], m4 = acc[1][r], m5 = acc[2][r];
        float s0 = m4 * lc3;
        float s1 = 0.5f * m4 * m3;
        o   += m5 * (lcA + 0.5f * s0 + (1.f/3.f) * s1);
        a3  += m5 * (g4 + 0.5f * m4);
        aA  += m5;
        lcA += s0 + s1;
        g4  += m4;
        lc3 += m3;
      }
      Ao[j] += o;
      Ba3[j] = a3; BaA[j] = aA; Bd3[j] = lc3; BdA[j] = lcA; BtA3[j] = g4;
    }
  }

  // ---- phase C: k 6..9, scan chain C, assemble run maps, compose in-reg ----
  float tot[NQ];
  {
    f32x16v acc[4];
    mfma_phase_pf<6, 4>(kwb, ah, al, l, ub, acc);
#pragma unroll
    for (int j = 0; j < 4; ++j) {
      float o = 0.f, a6 = 0.f, aP = 0.f, aQ = 0.f;
      float lc6 = 0.f, lcP = 0.f, lcQ = 0.f, g7 = 0.f, g8 = 0.f, hh = 0.f;
#pragma unroll
      for (int i = 0; i < 4; ++i) {
        const int r = 4 * j + i;
        float m6 = acc[0][r], m7 = acc[1][r], m8 = acc[2][r], m9 = acc[3][r];
        float p0 = m7 * lc6;
        float p1 = 0.5f * m7 * m6;
        float q0 = m8 * lcP;
        float q1 = 0.5f * m8 * p0;
        float q2 = (1.f/3.f) * m8 * p1;
        o   += m9 * (lcQ + 0.5f * q0 + (1.f/3.f) * q1 + 0.25f * q2);
        a6  += m9 * (hh + m8 * (0.5f * g7 + (1.f/6.f) * m7));
        aP  += m9 * (g8 + 0.5f * m8);
        aQ  += m9;
        hh  += m8 * (g7 + 0.5f * m7);   // exclusive g7, before update
        lcP += p0 + p1;
        lcQ += q0 + q1 + q2;
        g7 += m7; g8 += m8; lc6 += m6;
      }
      // full 17-param map for this 4-row run (rows 4g..4g+3, g = 2j+hi8)
      float mj[NQ];
      mj[Qo] = Ao[j] + o;
      mj[Qa1] = Aa1[j]; mj[Qa3] = Ba3[j]; mj[QaA] = BaA[j];
      mj[Qa6] = a6;     mj[QaP] = aP;     mj[QaQ] = aQ;
      mj[Qd1] = Ad1[j]; mj[Qd3] = Bd3[j]; mj[QdA] = BdA[j];
      mj[Qd6] = lc6;    mj[QdP] = lcP;    mj[QdQ] = lcQ;
      mj[QtA3] = BtA3[j]; mj[QtP6] = g7;  mj[QtQP] = g8; mj[QtQ6] = hh;

      // exchange with partner lane (g even <-> g odd) and compose 8-row map
      float q1v[NQ], q2v[NQ], m8r[NQ];
#pragma unroll
      for (int q = 0; q < NQ; ++q) {
        float oth = __shfl_xor(mj[q], 32);
        q1v[q] = hi8 ? oth : mj[q];       // even g = earlier rows
        q2v[q] = hi8 ? mj[q] : oth;
      }
      compose_maps(q1v, q2v, m8r);

      if (j == 0) {
#pragma unroll
        for (int q = 0; q < NQ; ++q) tot[q] = m8r[q];
      } else {
        float nt_[NQ];
        compose_maps(tot, m8r, nt_);
#pragma unroll
        for (int q = 0; q < NQ; ++q) tot[q] = nt_[q];
      }
    }
  }

  // ---- write the two 32-row maps (one per rt) into LDS (raw area is dead) --
  if (hi8 == 0) {
    float* p = &rawf[(rt * NQ) * NU + colbase];
#pragma unroll
    for (int q = 0; q < NQ; ++q) p[q * NU] = tot[q];
  }
  __syncthreads();

  // ---- final compose rt0 o rt1 -> 64-row WG map -> ws ----
  if (tid < NU) {
    const int uu = tid;
    float q1v[NQ], q2v[NQ], rv[NQ];
#pragma unroll
    for (int q = 0; q < NQ; ++q) {
      q1v[q] = rawf[(0 * NQ + q) * NU + uu];
      q2v[q] = rawf[(1 * NQ + q) * NU + uu];
    }
    compose_maps(q1v, q2v, rv);
    float* p = &wmaps[(((size_t)b * NCC + c) * NQ) * NU + uu];
#pragma unroll
    for (int q = 0; q < NQ; ++q) p[q * NU] = rv[q];
  }
}

// ---- partial fold: each (b, seg, u) composes 8 consecutive chunk maps ----
__global__ __launch_bounds__(256)
void lrsig_partial_kernel(const float* __restrict__ wmaps,
                          float* __restrict__ part)
{
  const int b   = blockIdx.x;          // 32 blocks
  const int seg = threadIdx.x >> 6;    // 0..3
  const int u   = threadIdx.x & 63;
  float tot[NQ];
  {
    const float* p0 = &wmaps[(((size_t)b * NCC + seg * 8) * NQ) * NU + u];
#pragma unroll
    for (int q = 0; q < NQ; ++q) tot[q] = p0[q * NU];
  }
  for (int i = 1; i < 8; ++i) {
    const float* p = &wmaps[(((size_t)b * NCC + seg * 8 + i) * NQ) * NU + u];
    float m[NQ], r[NQ];
#pragma unroll
    for (int q = 0; q < NQ; ++q) m[q] = p[q * NU];
    compose_maps(tot, m, r);
#pragma unroll
    for (int q = 0; q < NQ; ++q) tot[q] = r[q];
  }
  float* d = &part[(((size_t)b * NSEG + seg) * NQ) * NU + u];
#pragma unroll
  for (int q = 0; q < NQ; ++q) d[q * NU] = tot[q];
}

// ---- final: fold the 4 segment maps per (b,u), emit out ----
__global__ __launch_bounds__(64)
void lrsig_final_kernel(const float* __restrict__ part,
                        float* __restrict__ out)
{
  const int b = blockIdx.x;            // 32 blocks x 64 threads
  const int u = threadIdx.x;
  float c1 = 0.f, c3 = 0.f, cA = 0.f, c6 = 0.f, cP = 0.f, cQ = 0.f, o = 0.f;
#pragma unroll
  for (int s = 0; s < NSEG; ++s) {
    const float* p = &part[(((size_t)b * NSEG + s) * NQ) * NU + u];
    float q[NQ];
#pragma unroll
    for (int i = 0; i < NQ; ++i) q[i] = p[i * NU];
    o  += q[0] + q[1]*c1 + q[2]*c3 + q[3]*cA + q[4]*c6 + q[5]*cP + q[6]*cQ;
    cA += q[13]*c3 + q[9];             // uses c3_in
    cQ += q[15]*cP + q[16]*c6 + q[12]; // uses cP_in, c6_in
    cP += q[14]*c6 + q[11];            // uses c6_in
    c1 += q[7]; c3 += q[8]; c6 += q[10];
  }
  out[b * 64 + u] = o;
}

extern "C" void kernel_launch(void* const* d_in, const int* in_sizes, int n_in,
                              void* d_out, int out_size, void* d_ws, size_t ws_size,
                              hipStream_t stream) {
  const float* X  = (const float*)d_in[0];   // (32, 2048, 63) fp32
  const float* Kw = (const float*)d_in[1];   // (64, 10, 64)   fp32
  float* out = (float*)d_out;                // (32, 64)       fp32
  float* wmaps = (float*)d_ws;                                    // 4.45 MB
  unsigned short* kwb = (unsigned short*)((char*)d_ws + MAPS_BYTES); // 160 KB
  float* part = (float*)((char*)d_ws + MAPS_BYTES + KWB_BYTES);   // 557 KB

  hipLaunchKernelGGL(lrsig_prep_kernel, dim3(160), dim3(256), 0, stream,
                     Kw, kwb);
  hipLaunchKernelGGL(lrsig_chunk_kernel, dim3(NCC, 32), dim3(256), 0, stream,
                     X, kwb, wmaps);
  hipLaunchKernelGGL(lrsig_partial_kernel, dim3(32), dim3(256), 0, stream,
                     wmaps, part);
  hipLaunchKernelGGL(lrsig_final_kernel, dim3(32), dim3(64), 0, stream,
                     part, out);
}